// Round 1
// baseline (394.868 us; speedup 1.0000x reference)
//
#include <hip/hip_runtime.h>

// Problem constants
#define BB 256          // batch
#define FF 128          // features
#define NL 4            // layers
#define TT 2048         // trees per layer
#define DD 6            // depth
#define CC 100          // classes
#define LL 64           // leaves = 2^DD
#define RTOT 49152      // NL*TT*DD sel rows
#define ITOT 8192       // NL*TT (i,t) pairs
#define CPAD 112        // C padded to 7*16
#define KG 512          // split-K groups
#define ITPB 16         // it-pairs per K2 block

typedef short bf16x8 __attribute__((ext_vector_type(8)));
typedef float f32x4 __attribute__((ext_vector_type(4)));

static __device__ inline unsigned short f2bf(float f) {
    unsigned u = __float_as_uint(f);
    u += 0x7fffu + ((u >> 16) & 1u);   // RNE
    return (unsigned short)(u >> 16);
}
static __device__ inline float bf2f(unsigned short h) {
    return __uint_as_float(((unsigned)h) << 16);
}

// ---------------------------------------------------------------------------
// Kernel 1: fv[it][d][b] = sigmoid(x[b,:] . sel_W[row,:] + sel_b[row])  (bf16)
// MFMA GEMM: M = sel rows (tile 128), N = b (tile 128), K = 128.
// ---------------------------------------------------------------------------
__global__ __launch_bounds__(256) void fv_kernel(
    const float* __restrict__ x, const float* __restrict__ selW,
    const float* __restrict__ selb, unsigned short* __restrict__ fv)
{
    __shared__ unsigned short wt[128 * 136]; // sel_W tile bf16, padded stride
    __shared__ unsigned short xt[128 * 136]; // x tile bf16
    __shared__ float sb[128];

    const int tid = threadIdx.x;
    const int m0 = blockIdx.x * 128;  // sel row base
    const int n0 = blockIdx.y * 128;  // b base

    // stage: 128x128 fp32 -> bf16, both operands (4096 float4 each)
    for (int pass = 0; pass < 16; ++pass) {
        int idx = pass * 256 + tid;
        int r = idx >> 5, f4 = idx & 31;
        float4 v = *((const float4*)(selW + (size_t)(m0 + r) * FF) + f4);
        ushort4 h;
        h.x = f2bf(v.x); h.y = f2bf(v.y); h.z = f2bf(v.z); h.w = f2bf(v.w);
        *(ushort4*)(wt + r * 136 + f4 * 4) = h;
        float4 vx = *((const float4*)(x + (size_t)(n0 + r) * FF) + f4);
        ushort4 hx;
        hx.x = f2bf(vx.x); hx.y = f2bf(vx.y); hx.z = f2bf(vx.z); hx.w = f2bf(vx.w);
        *(ushort4*)(xt + r * 136 + f4 * 4) = hx;
    }
    if (tid < 128) sb[tid] = selb[m0 + tid];
    __syncthreads();

    const int w = tid >> 6, lane = tid & 63;
    const int q = lane >> 4, l15 = lane & 15;
    const int mq = w & 1, nq = w >> 1;   // 2x2 wave grid, 64x64 quadrant each

    f32x4 zero4 = {0.f, 0.f, 0.f, 0.f};
    f32x4 acc[4][4];
    for (int i = 0; i < 4; ++i)
        for (int j = 0; j < 4; ++j) acc[i][j] = zero4;

    for (int ch = 0; ch < 4; ++ch) {          // K chunks of 32
        bf16x8 a[4];
        for (int ms = 0; ms < 4; ++ms)
            a[ms] = *(const bf16x8*)(wt + (mq * 64 + ms * 16 + l15) * 136 + ch * 32 + q * 8);
        for (int ns = 0; ns < 4; ++ns) {
            bf16x8 bfr = *(const bf16x8*)(xt + (nq * 64 + ns * 16 + l15) * 136 + ch * 32 + q * 8);
            for (int ms = 0; ms < 4; ++ms)
                acc[ms][ns] = __builtin_amdgcn_mfma_f32_16x16x32_bf16(a[ms], bfr, acc[ms][ns], 0, 0, 0);
        }
    }

    // epilogue: sigmoid, scatter to fv[it][d][b]
    for (int ms = 0; ms < 4; ++ms) {
        int rowl = mq * 64 + ms * 16 + q * 4;
        for (int ns = 0; ns < 4; ++ns) {
            int b = n0 + nq * 64 + ns * 16 + l15;
            for (int reg = 0; reg < 4; ++reg) {
                int row = m0 + rowl + reg;
                float z = acc[ms][ns][reg] + sb[rowl + reg];
                float e = __expf(-z);
                float p = 1.0f / (1.0f + e);
                int i = row / 12288;
                int rr = row - i * 12288;
                int t = rr / 6;
                int d = rr - t * 6;
                size_t it = (size_t)i * TT + t;
                fv[it * 1536 + d * 256 + b] = f2bf(p);
            }
        }
    }
}

// ---------------------------------------------------------------------------
// Kernel 2: split-K GEMM out = leaf(onthefly) @ out_W^T
// block = 256 thr (4 waves), out tile = 256 b x 112 c, 16 it-pairs per block.
// ---------------------------------------------------------------------------
__global__ __launch_bounds__(256) void main_gemm(
    const unsigned short* __restrict__ fv, const float* __restrict__ outW,
    float* __restrict__ part)
{
    __shared__ unsigned short leaf[256 * 72]; // 36864 B, row stride 72 bf16 (=36 dw, %32==4 -> free)
    __shared__ unsigned short wt[CPAD * 72];  // 16128 B

    const int tid = threadIdx.x;
    const int kg = blockIdx.x;
    const int w = tid >> 6, lane = tid & 63;
    const int q = lane >> 4, l15 = lane & 15;

    f32x4 zero4 = {0.f, 0.f, 0.f, 0.f};
    f32x4 acc[4][7];
    for (int i = 0; i < 4; ++i)
        for (int j = 0; j < 7; ++j) acc[i][j] = zero4;

    for (int itl = 0; itl < ITPB; ++itl) {
        const int it = kg * ITPB + itl;

        // p0..p5 for b = tid (coalesced bf16 loads)
        const unsigned short* fvp = fv + (size_t)it * 1536 + tid;
        float p0 = bf2f(fvp[0]);
        float p1 = bf2f(fvp[256]);
        float p2 = bf2f(fvp[512]);
        float p3 = bf2f(fvp[768]);
        float p4 = bf2f(fvp[1024]);
        float p5 = bf2f(fvp[1280]);

        // stage out_W tile: 112 c x 64 l  (fp32 -> bf16), zeros for c>=100
        {
            int cc = tid >> 4, f4 = tid & 15;
            for (int pass = 0; pass < 7; ++pass) {
                int c = pass * 16 + cc;
                float4 v = make_float4(0.f, 0.f, 0.f, 0.f);
                if (c < CC)
                    v = *((const float4*)(outW + (size_t)c * 524288 + (size_t)it * 64) + f4);
                ushort4 h;
                h.x = f2bf(v.x); h.y = f2bf(v.y); h.z = f2bf(v.z); h.w = f2bf(v.w);
                *(ushort4*)(wt + c * 72 + f4 * 4) = h;
            }
        }

        // leaf generation for b = tid: tree-factorized products
        {
            float q0 = 1.f - p0, q1 = 1.f - p1, q2 = 1.f - p2;
            float q3 = 1.f - p3, q4 = 1.f - p4, q5 = 1.f - p5;
            float A[4]  = {p0 * p1, p0 * q1, q0 * p1, q0 * q1};   // bits d0,d1 (l>>4)
            float B2[4] = {p2 * p3, p2 * q3, q2 * p3, q2 * q3};   // bits d2,d3
            float C2[4] = {p4 * p5, p4 * q5, q4 * p5, q4 * q5};   // bits d4,d5
            float BC[16];
            for (int m = 0; m < 16; ++m) BC[m] = B2[m >> 2] * C2[m & 3];
            unsigned short* row = leaf + tid * 72;
            for (int j = 0; j < 8; ++j) {
                uint4 dw;
                unsigned int* dwp = (unsigned int*)&dw;
                for (int e = 0; e < 4; ++e) {
                    int l0 = j * 8 + 2 * e;
                    float v0 = A[l0 >> 4] * BC[l0 & 15];
                    float v1 = A[(l0 + 1) >> 4] * BC[(l0 + 1) & 15];
                    dwp[e] = (unsigned)f2bf(v0) | ((unsigned)f2bf(v1) << 16);
                }
                *(uint4*)(row + j * 8) = dw;
            }
        }
        __syncthreads();

        // MFMA: wave w owns m-subtiles w*4..w*4+3 (64 b rows)
        for (int ch = 0; ch < 2; ++ch) {
            bf16x8 a[4];
            for (int ms = 0; ms < 4; ++ms)
                a[ms] = *(const bf16x8*)(leaf + (w * 64 + ms * 16 + l15) * 72 + ch * 32 + q * 8);
            for (int nt = 0; nt < 7; ++nt) {
                bf16x8 bb = *(const bf16x8*)(wt + (nt * 16 + l15) * 72 + ch * 32 + q * 8);
                for (int ms = 0; ms < 4; ++ms)
                    acc[ms][nt] = __builtin_amdgcn_mfma_f32_16x16x32_bf16(a[ms], bb, acc[ms][nt], 0, 0, 0);
            }
        }
        __syncthreads();
    }

    // write fp32 partials: part[kg][b][c]
    float* pbase = part + (size_t)kg * (256 * CPAD);
    for (int ms = 0; ms < 4; ++ms) {
        int brow = w * 64 + ms * 16 + q * 4;
        for (int nt = 0; nt < 7; ++nt) {
            int c = nt * 16 + l15;
            for (int reg = 0; reg < 4; ++reg)
                pbase[(size_t)(brow + reg) * CPAD + c] = acc[ms][nt][reg];
        }
    }
}

// ---------------------------------------------------------------------------
// Kernel 3: out[b][c] = sum_kg part[kg][b][c] + out_b[c]
// block: 64 outputs x 4-way kg split; grid 400
// ---------------------------------------------------------------------------
__global__ __launch_bounds__(256) void reduce_k(
    const float* __restrict__ part, const float* __restrict__ outb,
    float* __restrict__ out)
{
    __shared__ float red[256];
    const int o = blockIdx.x * 64 + (threadIdx.x & 63);
    const int kq = threadIdx.x >> 6;
    const int b = o / 100, c = o - b * 100;
    const float* p = part + (size_t)b * CPAD + c + (size_t)kq * 128 * (256 * CPAD);
    float s = 0.f;
    for (int i = 0; i < 128; ++i) s += p[(size_t)i * (256 * CPAD)];
    red[threadIdx.x] = s;
    __syncthreads();
    if (threadIdx.x < 64) {
        float r = red[threadIdx.x] + red[threadIdx.x + 64] +
                  red[threadIdx.x + 128] + red[threadIdx.x + 192];
        out[o] = r + outb[c];
    }
}

extern "C" void kernel_launch(void* const* d_in, const int* in_sizes, int n_in,
                              void* d_out, int out_size, void* d_ws, size_t ws_size,
                              hipStream_t stream) {
    const float* x    = (const float*)d_in[0];
    const float* selW = (const float*)d_in[1];
    const float* selb = (const float*)d_in[2];
    const float* outW = (const float*)d_in[3];
    const float* outb = (const float*)d_in[4];
    float* out = (float*)d_out;

    // ws layout: fv bf16 [8192*1536] = 25,165,824 B ; part fp32 [512*256*112] = 58,720,256 B
    unsigned short* fv = (unsigned short*)d_ws;
    float* part = (float*)((char*)d_ws + 25165824);

    fv_kernel<<<dim3(RTOT / 128, BB / 128), 256, 0, stream>>>(x, selW, selb, fv);
    main_gemm<<<KG, 256, 0, stream>>>(fv, outW, part);
    reduce_k<<<400, 256, 0, stream>>>(part, outb, out);
}

// Round 2
// 355.521 us; speedup vs baseline: 1.1107x; 1.1107x over previous
//
#include <hip/hip_runtime.h>

// Problem constants
#define BB 256          // batch
#define FF 128          // features
#define CC 100          // classes
#define KG 512          // split-K groups (blocks of main_gemm)
#define ITPB 16         // it-pairs per main_gemm block (KG*ITPB = 8192)

typedef short bf16x8 __attribute__((ext_vector_type(8)));
typedef float f32x4 __attribute__((ext_vector_type(4)));

// Raw barrier: waits LDS ops only, leaves global loads (vmcnt) in flight.
// __syncthreads() would emit s_waitcnt vmcnt(0) and drain the prefetch.
#define LDS_BARRIER() asm volatile("s_waitcnt lgkmcnt(0)\n\ts_barrier" ::: "memory")

static __device__ inline unsigned short f2bf(float f) {
    unsigned u = __float_as_uint(f);
    u += 0x7fffu + ((u >> 16) & 1u);   // RNE
    return (unsigned short)(u >> 16);
}
static __device__ inline float bf2f(unsigned short h) {
    return __uint_as_float(((unsigned)h) << 16);
}

// ---------------------------------------------------------------------------
// Kernel 1: fv[row][b] = sigmoid(x[b,:] . sel_W[row,:] + sel_b[row])  (bf16)
// row = it*6 + d, so fv[row*256+b] == fv[it][d][b] — no div/mod needed.
// ---------------------------------------------------------------------------
__global__ __launch_bounds__(256) void fv_kernel(
    const float* __restrict__ x, const float* __restrict__ selW,
    const float* __restrict__ selb, unsigned short* __restrict__ fvout)
{
    __shared__ unsigned short wt[128 * 136]; // sel_W tile bf16, padded stride
    __shared__ unsigned short xt[128 * 136]; // x tile bf16
    __shared__ float sb[128];

    const int tid = threadIdx.x;
    const int m0 = blockIdx.x * 128;  // sel row base
    const int n0 = blockIdx.y * 128;  // b base

    #pragma unroll 4
    for (int pass = 0; pass < 16; ++pass) {
        int idx = pass * 256 + tid;
        int r = idx >> 5, f4 = idx & 31;
        float4 v = *((const float4*)(selW + (size_t)(m0 + r) * FF) + f4);
        ushort4 h;
        h.x = f2bf(v.x); h.y = f2bf(v.y); h.z = f2bf(v.z); h.w = f2bf(v.w);
        *(ushort4*)(wt + r * 136 + f4 * 4) = h;
        float4 vx = *((const float4*)(x + (size_t)(n0 + r) * FF) + f4);
        ushort4 hx;
        hx.x = f2bf(vx.x); hx.y = f2bf(vx.y); hx.z = f2bf(vx.z); hx.w = f2bf(vx.w);
        *(ushort4*)(xt + r * 136 + f4 * 4) = hx;
    }
    if (tid < 128) sb[tid] = selb[m0 + tid];
    __syncthreads();

    const int w = tid >> 6, lane = tid & 63;
    const int q = lane >> 4, l15 = lane & 15;
    const int mq = w & 1, nq = w >> 1;   // 2x2 wave grid, 64x64 quadrant each

    f32x4 zero4 = {0.f, 0.f, 0.f, 0.f};
    f32x4 acc[4][4];
    #pragma unroll
    for (int i = 0; i < 4; ++i)
        #pragma unroll
        for (int j = 0; j < 4; ++j) acc[i][j] = zero4;

    #pragma unroll
    for (int ch = 0; ch < 4; ++ch) {          // K chunks of 32
        bf16x8 a[4];
        #pragma unroll
        for (int ms = 0; ms < 4; ++ms)
            a[ms] = *(const bf16x8*)(wt + (mq * 64 + ms * 16 + l15) * 136 + ch * 32 + q * 8);
        #pragma unroll
        for (int ns = 0; ns < 4; ++ns) {
            bf16x8 bfr = *(const bf16x8*)(xt + (nq * 64 + ns * 16 + l15) * 136 + ch * 32 + q * 8);
            #pragma unroll
            for (int ms = 0; ms < 4; ++ms)
                acc[ms][ns] = __builtin_amdgcn_mfma_f32_16x16x32_bf16(a[ms], bfr, acc[ms][ns], 0, 0, 0);
        }
    }

    // epilogue: sigmoid, store at row*256+b (direct index, no div)
    #pragma unroll
    for (int ms = 0; ms < 4; ++ms) {
        int rowl = mq * 64 + ms * 16 + q * 4;
        #pragma unroll
        for (int ns = 0; ns < 4; ++ns) {
            int b = n0 + nq * 64 + ns * 16 + l15;
            #pragma unroll
            for (int reg = 0; reg < 4; ++reg) {
                int row = m0 + rowl + reg;
                float z = acc[ms][ns][reg] + sb[rowl + reg];
                float p = 1.0f / (1.0f + __expf(-z));
                fvout[(size_t)row * 256 + b] = f2bf(p);
            }
        }
    }
}

// ---------------------------------------------------------------------------
// Kernel 2: split-K GEMM out = leaf(on-the-fly) @ out_W^T, pipelined K-loop.
// block = 256 thr (4 waves), out tile = 256 b x 112 c, 16 it-pairs per block.
// Partials layout: part[b][kg][c]  (c padded to 112) for contiguous reduce.
// ---------------------------------------------------------------------------
__global__ __launch_bounds__(256, 2) void main_gemm(
    const unsigned short* __restrict__ fv, const float* __restrict__ outW,
    float* __restrict__ part)
{
    __shared__ unsigned short leaf[256 * 72]; // 36864 B (stride 144 B, 16B-aligned rows)
    __shared__ unsigned short wt[112 * 72];   // 16128 B

    const int tid = threadIdx.x;
    const int kg = blockIdx.x;
    const int w = tid >> 6, lane = tid & 63;
    const int q = lane >> 4, l15 = lane & 15;
    const int cc = tid >> 4, f4 = tid & 15;

    f32x4 zero4 = {0.f, 0.f, 0.f, 0.f};
    f32x4 acc[4][7];
    #pragma unroll
    for (int i = 0; i < 4; ++i)
        #pragma unroll
        for (int j = 0; j < 7; ++j) acc[i][j] = zero4;

    // -------- prologue: prefetch tile 0 into regs --------
    float4 wv[7];
    unsigned short pv[6];
    {
        const int it = kg * ITPB;
        #pragma unroll
        for (int pass = 0; pass < 7; ++pass) {
            const int c = pass * 16 + cc;
            float4 v = make_float4(0.f, 0.f, 0.f, 0.f);
            if (c < CC)
                v = *((const float4*)(outW + (size_t)c * 524288 + (size_t)it * 64) + f4);
            wv[pass] = v;   // c>=100 lanes stay zero forever (never reloaded)
        }
        const unsigned short* fp = fv + (size_t)it * 1536 + tid;
        #pragma unroll
        for (int d = 0; d < 6; ++d) pv[d] = fp[d * 256];
    }

    for (int itl = 0; itl < ITPB; ++itl) {
        LDS_BARRIER();   // prev iteration's MFMA LDS reads complete (lgkm only)

        // (1) consume wv: convert fp32 -> bf16, stage wt tile
        #pragma unroll
        for (int pass = 0; pass < 7; ++pass) {
            const int c = pass * 16 + cc;
            ushort4 h;
            h.x = f2bf(wv[pass].x); h.y = f2bf(wv[pass].y);
            h.z = f2bf(wv[pass].z); h.w = f2bf(wv[pass].w);
            *(ushort4*)(wt + c * 72 + f4 * 4) = h;
        }

        // (2) consume pv: leaf generation for b = tid (tree-factorized)
        {
            float p0 = bf2f(pv[0]), p1 = bf2f(pv[1]), p2 = bf2f(pv[2]);
            float p3 = bf2f(pv[3]), p4 = bf2f(pv[4]), p5 = bf2f(pv[5]);
            float q0 = 1.f - p0, q1 = 1.f - p1, q2 = 1.f - p2;
            float q3 = 1.f - p3, q4 = 1.f - p4, q5 = 1.f - p5;
            float A[4]  = {p0 * p1, p0 * q1, q0 * p1, q0 * q1};
            float B2[4] = {p2 * p3, p2 * q3, q2 * p3, q2 * q3};
            float C2[4] = {p4 * p5, p4 * q5, q4 * p5, q4 * q5};
            float BC[16];
            #pragma unroll
            for (int m = 0; m < 16; ++m) BC[m] = B2[m >> 2] * C2[m & 3];
            unsigned short* row = leaf + tid * 72;
            #pragma unroll
            for (int j = 0; j < 8; ++j) {
                uint4 dw;
                unsigned int* dwp = (unsigned int*)&dw;
                #pragma unroll
                for (int e = 0; e < 4; ++e) {
                    int l0 = j * 8 + 2 * e;
                    float v0 = A[l0 >> 4] * BC[l0 & 15];
                    float v1 = A[(l0 + 1) >> 4] * BC[(l0 + 1) & 15];
                    dwp[e] = (unsigned)f2bf(v0) | ((unsigned)f2bf(v1) << 16);
                }
                *(uint4*)(row + j * 8) = dw;
            }
        }

        // (3) reissue prefetch for tile itl+1 (wraps on last iter; harmless)
        {
            const int itn = kg * ITPB + ((itl + 1) & (ITPB - 1));
            #pragma unroll
            for (int pass = 0; pass < 7; ++pass) {
                const int c = pass * 16 + cc;
                if (c < CC)
                    wv[pass] = *((const float4*)(outW + (size_t)c * 524288 + (size_t)itn * 64) + f4);
            }
            const unsigned short* fp = fv + (size_t)itn * 1536 + tid;
            #pragma unroll
            for (int d = 0; d < 6; ++d) pv[d] = fp[d * 256];
        }

        LDS_BARRIER();   // LDS writes visible; prefetch loads stay in flight

        // (4) MFMA over LDS
        #pragma unroll
        for (int ch = 0; ch < 2; ++ch) {
            bf16x8 a[4];
            #pragma unroll
            for (int ms = 0; ms < 4; ++ms)
                a[ms] = *(const bf16x8*)(leaf + (w * 64 + ms * 16 + l15) * 72 + ch * 32 + q * 8);
            #pragma unroll
            for (int nt = 0; nt < 7; ++nt) {
                bf16x8 bb = *(const bf16x8*)(wt + (nt * 16 + l15) * 72 + ch * 32 + q * 8);
                #pragma unroll
                for (int ms = 0; ms < 4; ++ms)
                    acc[ms][nt] = __builtin_amdgcn_mfma_f32_16x16x32_bf16(a[ms], bb, acc[ms][nt], 0, 0, 0);
            }
        }
    }

    // epilogue: part[b][kg][c]
    #pragma unroll
    for (int ms = 0; ms < 4; ++ms) {
        const int brow = w * 64 + ms * 16 + q * 4;
        #pragma unroll
        for (int nt = 0; nt < 7; ++nt) {
            const int c = nt * 16 + l15;
            #pragma unroll
            for (int reg = 0; reg < 4; ++reg)
                part[((size_t)(brow + reg) * KG + kg) * 112 + c] = acc[ms][nt][reg];
        }
    }
}

// ---------------------------------------------------------------------------
// Kernel 3: out[b][c] = sum_kg part[b][kg][c] + out_b[c]
// One block per b; slice is 229376 contiguous bytes; float4 index = i*252+tid
// (exactly contiguous since tid = kgsub*28 + c4). No pow-2 stride camping.
// ---------------------------------------------------------------------------
__global__ __launch_bounds__(256) void reduce_k(
    const float* __restrict__ part, const float* __restrict__ outb,
    float* __restrict__ out)
{
    __shared__ float red[9 * 112];
    const int b = blockIdx.x;
    const int tid = threadIdx.x;
    const float* slice = part + (size_t)b * (KG * 112);

    if (tid < 252) {
        const int kgsub = tid / 28;          // 0..8
        const int c4 = tid - kgsub * 28;     // 0..27
        f32x4 s = {0.f, 0.f, 0.f, 0.f};
        #pragma unroll 8
        for (int i = 0; i < 56; ++i) {       // kg = i*9 + kgsub  (0..503)
            f32x4 v = *((const f32x4*)slice + (i * 252 + tid));
            s += v;
        }
        if (kgsub < 8) {                     // tail kg = 504..511
            f32x4 v = *((const f32x4*)slice + ((504 + kgsub) * 28 + c4));
            s += v;
        }
        *(f32x4*)(red + kgsub * 112 + c4 * 4) = s;
    }
    __syncthreads();
    if (tid < CC) {
        float r = outb[tid];
        #pragma unroll
        for (int k = 0; k < 9; ++k) r += red[k * 112 + tid];
        out[b * CC + tid] = r;
    }
}

extern "C" void kernel_launch(void* const* d_in, const int* in_sizes, int n_in,
                              void* d_out, int out_size, void* d_ws, size_t ws_size,
                              hipStream_t stream) {
    const float* x    = (const float*)d_in[0];
    const float* selW = (const float*)d_in[1];
    const float* selb = (const float*)d_in[2];
    const float* outW = (const float*)d_in[3];
    const float* outb = (const float*)d_in[4];
    float* out = (float*)d_out;

    // ws layout: fv bf16 [49152*256] = 25,165,824 B ; part fp32 [256][512][112] = 58,720,256 B
    unsigned short* fv = (unsigned short*)d_ws;
    float* part = (float*)((char*)d_ws + 25165824);

    fv_kernel<<<dim3(384, 2), 256, 0, stream>>>(x, selW, selb, fv);
    main_gemm<<<KG, 256, 0, stream>>>(fv, outW, part);
    reduce_k<<<BB, 256, 0, stream>>>(part, outb, out);
}